// Round 12
// baseline (96.432 us; speedup 1.0000x reference)
//
#include <hip/hip_runtime.h>
#include <math.h>

static constexpr int M = 4096;   // batch rows
static constexpr int C = 512;    // classes
static constexpr int D = 128;    // feature dim
static constexpr float ALPHA = 0.5f;

// ---------------- workspace layout (bytes) ----------------
// label     : int[M]       @ 0       fully written by k_label
// d_pos     : float[M]     @ 16384   plain-stored by unique owner thread
// loss_part : float[M*16]  @ 32768   plain-stored, one slot per (m, c-chunk)
// no zero-init, no global atomics, no fences.
static constexpr size_t WS_LABEL = 0;
static constexpr size_t WS_DPOS  = 16384;
static constexpr size_t WS_LPART = 32768;

// ---- kernel 1: per-row argmax of onehot -> label[M] ----
// one wave per row; 4 rows per 256-thread block.
__global__ __launch_bounds__(256) void k_label(
    const float* __restrict__ onehot, int* __restrict__ label)
{
    int gtid = blockIdx.x * 256 + threadIdx.x;
    int row  = gtid >> 6;            // grid = M/4 -> row < M always
    int lane = threadIdx.x & 63;

    const float4* oh = reinterpret_cast<const float4*>(onehot + (size_t)row * C);
    float4 a = oh[lane * 2 + 0];
    float4 b = oh[lane * 2 + 1];
    int lbl = -1;
    if (a.x > 0.5f) lbl = lane * 8 + 0;
    if (a.y > 0.5f) lbl = lane * 8 + 1;
    if (a.z > 0.5f) lbl = lane * 8 + 2;
    if (a.w > 0.5f) lbl = lane * 8 + 3;
    if (b.x > 0.5f) lbl = lane * 8 + 4;
    if (b.y > 0.5f) lbl = lane * 8 + 5;
    if (b.z > 0.5f) lbl = lane * 8 + 6;
    if (b.w > 0.5f) lbl = lane * 8 + 7;
    #pragma unroll
    for (int off = 32; off > 0; off >>= 1)
        lbl = max(lbl, __shfl_xor(lbl, off));
    if (lane == 0) label[row] = lbl;
}

// ---- kernel 2: 32x32 L1-distance tile, SINGLE-WAVE blocks ----
// grid = 128 m-tiles x 16 c-chunks = 2048 blocks x 64 threads (8 blocks/CU,
// 16 KB LDS -> fully resident). 4m x 4c per thread (0.5 LDS-reads/output).
// __syncthreads in a 1-wave block is ~free: no inter-wave barrier drain.
// Swizzle: physical quad holds logical q = (Q&15) ^ ((row>>2)&7), applied to
// the GLOBAL source address -> linear conflict-free ds_write_b128; reads use
// key ty (x) / tx (c): 8 distinct bank-quads x 8-lane broadcast, conflict-free.
__global__ __launch_bounds__(64) void k_dist(
    const float* __restrict__ x0, const float* __restrict__ centers,
    const int* __restrict__ label,
    float* __restrict__ d_pos, float* __restrict__ loss_part)
{
    __shared__ float xs[32 * 64];    // 8 KB (one 64-d chunk of 32 m-rows)
    __shared__ float cs[32 * 64];    // 8 KB

    int tid = threadIdx.x;           // 0..63, one wave
    int b   = blockIdx.x;
    int mb  = b & 127;               // 128 m-tiles of 32 rows
    int cb  = b >> 7;                // 16 c-chunks of 32
    int m0  = mb * 32, c0 = cb * 32;
    int tx  = tid & 7;               // -> 4 c rows
    int ty  = tid >> 3;              // -> 4 m rows

    // early: labels for this thread's 4 m-rows (epilogue operand)
    int lbls[4];
    #pragma unroll
    for (int i = 0; i < 4; i++) lbls[i] = label[m0 + ty * 4 + i];

    // ===== issue chunk-0 loads (8 quads per tile per thread) =====
    float4 rx[8], rc[8];
    #pragma unroll
    for (int kk = 0; kk < 8; ++kk) {
        int Q   = kk * 64 + tid;                 // 0..511
        int row = Q >> 4;                        // 0..31
        int q   = (Q & 15) ^ ((row >> 2) & 7);   // pre-swizzled global source
        rx[kk] = *reinterpret_cast<const float4*>(
            x0      + (size_t)(m0 + row) * D + q * 4);
        rc[kk] = *reinterpret_cast<const float4*>(
            centers + (size_t)(c0 + row) * D + q * 4);
    }
    // write chunk0 -> LDS (linear, conflict-free)
    #pragma unroll
    for (int kk = 0; kk < 8; ++kk) {
        int e = (kk * 64 + tid) * 4;
        *reinterpret_cast<float4*>(xs + e) = rx[kk];
        *reinterpret_cast<float4*>(cs + e) = rc[kk];
    }
    // issue chunk-1 loads (hide under chunk-0 compute)
    #pragma unroll
    for (int kk = 0; kk < 8; ++kk) {
        int Q   = kk * 64 + tid;
        int row = Q >> 4;
        int q   = (Q & 15) ^ ((row >> 2) & 7);
        rx[kk] = *reinterpret_cast<const float4*>(
            x0      + (size_t)(m0 + row) * D + 64 + q * 4);
        rc[kk] = *reinterpret_cast<const float4*>(
            centers + (size_t)(c0 + row) * D + 64 + q * 4);
    }
    __syncthreads();

    float acc[4][4];
    #pragma unroll
    for (int i = 0; i < 4; i++)
        #pragma unroll
        for (int j = 0; j < 4; j++) acc[i][j] = 0.f;

    #pragma unroll 4
    for (int q = 0; q < 16; ++q) {               // chunk 0
        int xo = (q ^ ty) << 2;
        int co = (q ^ tx) << 2;
        float4 xa[4], ca[4];
        #pragma unroll
        for (int i = 0; i < 4; ++i)
            xa[i] = *reinterpret_cast<const float4*>(xs + (ty * 4 + i) * 64 + xo);
        #pragma unroll
        for (int j = 0; j < 4; ++j)
            ca[j] = *reinterpret_cast<const float4*>(cs + (tx * 4 + j) * 64 + co);
        #pragma unroll
        for (int i = 0; i < 4; ++i)
            #pragma unroll
            for (int j = 0; j < 4; ++j) {
                acc[i][j] += fabsf(xa[i].x - ca[j].x);   // v_sub+v_add(|mod|)
                acc[i][j] += fabsf(xa[i].y - ca[j].y);
                acc[i][j] += fabsf(xa[i].z - ca[j].z);
                acc[i][j] += fabsf(xa[i].w - ca[j].w);
            }
    }
    __syncthreads();

    // write chunk1 -> LDS
    #pragma unroll
    for (int kk = 0; kk < 8; ++kk) {
        int e = (kk * 64 + tid) * 4;
        *reinterpret_cast<float4*>(xs + e) = rx[kk];
        *reinterpret_cast<float4*>(cs + e) = rc[kk];
    }
    __syncthreads();

    #pragma unroll 4
    for (int q = 0; q < 16; ++q) {               // chunk 1
        int xo = (q ^ ty) << 2;
        int co = (q ^ tx) << 2;
        float4 xa[4], ca[4];
        #pragma unroll
        for (int i = 0; i < 4; ++i)
            xa[i] = *reinterpret_cast<const float4*>(xs + (ty * 4 + i) * 64 + xo);
        #pragma unroll
        for (int j = 0; j < 4; ++j)
            ca[j] = *reinterpret_cast<const float4*>(cs + (tx * 4 + j) * 64 + co);
        #pragma unroll
        for (int i = 0; i < 4; ++i)
            #pragma unroll
            for (int j = 0; j < 4; ++j) {
                acc[i][j] += fabsf(xa[i].x - ca[j].x);
                acc[i][j] += fabsf(xa[i].y - ca[j].y);
                acc[i][j] += fabsf(xa[i].z - ca[j].z);
                acc[i][j] += fabsf(xa[i].w - ca[j].w);
            }
    }

    // ===== epilogue: d_pos (unique owner) + per-chunk exp-sum partials =====
    #pragma unroll
    for (int i = 0; i < 4; i++) {
        float ps = 0.f;
        #pragma unroll
        for (int j = 0; j < 4; j++) {
            int cg = c0 + tx * 4 + j;
            float dist = acc[i][j];
            if (cg == lbls[i]) {
                d_pos[m0 + ty * 4 + i] = dist;       // unique writer per m
            } else {
                ps += __expf(-dist);
            }
        }
        #pragma unroll
        for (int off = 4; off > 0; off >>= 1)        // 8-lane tx group
            ps += __shfl_xor(ps, off);
        if (tx == 0)
            loss_part[(size_t)(m0 + ty * 4 + i) * 16 + cb] = ps;
    }
}

// ---- kernel 3: {gather center-update for class b} + {loss rows 8b..8b+7} ----
// grid = 512 blocks x 256 threads. Loss loads issued at entry (hide under the
// label scan + gather).
__global__ __launch_bounds__(256) void k_fin(
    const float* __restrict__ x0, const float* __restrict__ centers,
    const int* __restrict__ label,
    const float* __restrict__ d_pos, const float* __restrict__ loss_part,
    float* __restrict__ out_nc, float* __restrict__ loss_out)
{
    __shared__ int   list[1024];
    __shared__ float tmp[128];
    __shared__ int   lcount;

    int b   = blockIdx.x;
    int tid = threadIdx.x;

    // issue loss loads early (consumed at the end)
    int   m  = b * 8 + (tid >> 4);           // 8 rows per block, 16 lanes each
    float lp = 0.f, dp = 0.f;
    if (tid < 128) {
        lp = loss_part[(size_t)m * 16 + (tid & 15)];
        dp = d_pos[m];
    }

    // ----- center update for class b (LDS member list + gather) -----
    if (tid == 0) lcount = 0;
    __syncthreads();
    {
        const int4* lab4 = reinterpret_cast<const int4*>(label);
        #pragma unroll
        for (int t = 0; t < 4; ++t) {
            int4 v   = lab4[tid + 256 * t];
            int base = (tid + 256 * t) * 4;
            if (v.x == b) { int k = atomicAdd(&lcount, 1); if (k < 1024) list[k] = base + 0; }
            if (v.y == b) { int k = atomicAdd(&lcount, 1); if (k < 1024) list[k] = base + 1; }
            if (v.z == b) { int k = atomicAdd(&lcount, 1); if (k < 1024) list[k] = base + 2; }
            if (v.w == b) { int k = atomicAdd(&lcount, 1); if (k < 1024) list[k] = base + 3; }
        }
    }
    __syncthreads();
    {
        int n = min(lcount, 1024);
        int d = tid & 127;
        int p = tid >> 7;                  // 0/1: even/odd member indices
        float s = 0.f;
        int i = p;
        for (; i + 6 < n; i += 8) {        // 4 loads in flight per wait
            float a0 = x0[(size_t)list[i + 0] * D + d];
            float a1 = x0[(size_t)list[i + 2] * D + d];
            float a2 = x0[(size_t)list[i + 4] * D + d];
            float a3 = x0[(size_t)list[i + 6] * D + d];
            s += (a0 + a1) + (a2 + a3);
        }
        for (; i < n; i += 2) s += x0[(size_t)list[i] * D + d];
        if (p == 1) tmp[d] = s;
        __syncthreads();
        if (p == 0) {
            s += tmp[d];
            float ctr = centers[b * D + d];
            out_nc[b * D + d] = ctr - ALPHA * ((float)n * ctr - s) / ((float)n + 1.0f);
        }
    }

    // ----- finalize 8 losses (16-lane groups, intra-wave) -----
    if (tid < 128) {
        float s = lp;
        #pragma unroll
        for (int off = 8; off > 0; off >>= 1)
            s += __shfl_xor(s, off);
        if ((tid & 15) == 0)
            loss_out[m] = dp + log1pf(s);
    }
}

extern "C" void kernel_launch(void* const* d_in, const int* in_sizes, int n_in,
                              void* d_out, int out_size, void* d_ws, size_t ws_size,
                              hipStream_t stream)
{
    const float* x0      = (const float*)d_in[0];   // (M, D)
    const float* onehot  = (const float*)d_in[1];   // (M, C)
    const float* centers = (const float*)d_in[2];   // (C, D)
    float* out = (float*)d_out;                     // [0..M) loss, [M..) new_centers

    char* ws = (char*)d_ws;
    int*   label     = (int*)  (ws + WS_LABEL);
    float* d_pos     = (float*)(ws + WS_DPOS);
    float* loss_part = (float*)(ws + WS_LPART);

    k_label<<<M / 4, 256, 0, stream>>>(onehot, label);
    k_dist <<<2048,  64,  0, stream>>>(x0, centers, label, d_pos, loss_part);
    k_fin  <<<C,     256, 0, stream>>>(x0, centers, label, d_pos, loss_part,
                                       out + M, out);
}

// Round 13
// 93.661 us; speedup vs baseline: 1.0296x; 1.0296x over previous
//
#include <hip/hip_runtime.h>
#include <math.h>

static constexpr int M = 4096;   // batch rows
static constexpr int C = 512;    // classes
static constexpr int D = 128;    // feature dim
static constexpr float ALPHA = 0.5f;

// ---------------- workspace layout (bytes) ----------------
// label     : int[M]      @ 0       written by cb==0 blocks of k_dist
// d_pos     : float[M]    @ 16384   plain-stored by unique owner thread
// loss_part : float[M*8]  @ 32768   plain-stored, one slot per (m, c-chunk)
// no zero-init, no global atomics, no fences.
static constexpr size_t WS_LABEL = 0;
static constexpr size_t WS_DPOS  = 16384;
static constexpr size_t WS_LPART = 32768;

// ---- kernel 1: {per-tile label scan} + {32x64 L1-distance tile} ----
// grid = 128 m-tiles x 8 c-chunks = 1024 blocks x 256 threads (4 blocks/CU),
// 24 KB LDS. R11-proven tile geometry; label scan replaces the k_label
// dispatch: each block derives labels for its 32 rows from onehot directly
// (64 KB/block, L3-hot after the first c-chunk touches it).
__global__ __launch_bounds__(256) void k_dist(
    const float* __restrict__ x0, const float* __restrict__ centers,
    const float* __restrict__ onehot,
    int* __restrict__ label, float* __restrict__ d_pos,
    float* __restrict__ loss_part)
{
    __shared__ float xs[32 * 64];    // 8 KB
    __shared__ float cs[64 * 64];    // 16 KB
    __shared__ int   lbl_sm[32];

    int tid = threadIdx.x;
    int b   = blockIdx.x;
    int mb  = b & 127;          // 128 m tiles of 32 rows
    int cb  = b >> 7;           // 8 c chunks of 64
    int m0  = mb * 32, c0 = cb * 64;

    // ===== label scan: rows m0..m0+31 (overlaps nothing downstream needs) ====
    {
        int row  = tid >> 3;     // 0..31
        int part = tid & 7;      // 0..7 -> 64 cols each
        const float4* oh = reinterpret_cast<const float4*>(
            onehot + (size_t)(m0 + row) * C + part * 64);
        int lbl = -1;
        #pragma unroll
        for (int k = 0; k < 16; ++k) {
            float4 v = oh[k];
            int base = part * 64 + k * 4;
            if (v.x > 0.5f) lbl = base + 0;
            if (v.y > 0.5f) lbl = base + 1;
            if (v.z > 0.5f) lbl = base + 2;
            if (v.w > 0.5f) lbl = base + 3;
        }
        #pragma unroll
        for (int off = 4; off > 0; off >>= 1)    // 8-lane group max
            lbl = max(lbl, __shfl_xor(lbl, off));
        if (part == 0) {
            lbl_sm[row] = lbl;
            if (cb == 0) label[m0 + row] = lbl;  // for k_fin (next dispatch)
        }
    }

    // ===== distance tile (R11 geometry, swizzled staging) =====
    int tx = tid & 15;          // -> 4 c rows
    int ty = tid >> 4;          // 0..15 -> 2 m rows
    int xk = (ty >> 1) & 7;     // = (row>>2)&7 for rows ty*2+i, i<2
    int ck = tx & 7;            // = (row>>2)&7 for rows tx*4+j

    float acc[2][4];
    #pragma unroll
    for (int i = 0; i < 2; i++)
        #pragma unroll
        for (int j = 0; j < 4; j++) acc[i][j] = 0.f;

    for (int dc = 0; dc < 2; ++dc) {
        int d0 = dc * 64;
        __syncthreads();   // protects LDS; also publishes lbl_sm (dc==0)
        // stage x tile: 512 quads, 2 per thread (pre-swizzled global source)
        #pragma unroll
        for (int kk = 0; kk < 2; ++kk) {
            int Q   = kk * 256 + tid;
            int row = Q >> 4;
            int q   = (Q & 15) ^ ((row >> 2) & 7);
            *reinterpret_cast<float4*>(xs + Q * 4) =
                *reinterpret_cast<const float4*>(x0 + (size_t)(m0 + row) * D + d0 + q * 4);
        }
        // stage c tile: 1024 quads, 4 per thread
        #pragma unroll
        for (int kk = 0; kk < 4; ++kk) {
            int Q   = kk * 256 + tid;
            int row = Q >> 4;
            int q   = (Q & 15) ^ ((row >> 2) & 7);
            *reinterpret_cast<float4*>(cs + Q * 4) =
                *reinterpret_cast<const float4*>(centers + (size_t)(c0 + row) * D + d0 + q * 4);
        }
        __syncthreads();

        #pragma unroll 4
        for (int q = 0; q < 16; ++q) {
            int xo = (q ^ xk) << 2;
            int co = (q ^ ck) << 2;
            float4 xa[2], ca[4];
            #pragma unroll
            for (int i = 0; i < 2; ++i)
                xa[i] = *reinterpret_cast<const float4*>(xs + (ty * 2 + i) * 64 + xo);
            #pragma unroll
            for (int j = 0; j < 4; ++j)
                ca[j] = *reinterpret_cast<const float4*>(cs + (tx * 4 + j) * 64 + co);
            #pragma unroll
            for (int i = 0; i < 2; ++i)
                #pragma unroll
                for (int j = 0; j < 4; ++j) {
                    acc[i][j] += fabsf(xa[i].x - ca[j].x);   // v_sub+v_add(|mod|)
                    acc[i][j] += fabsf(xa[i].y - ca[j].y);
                    acc[i][j] += fabsf(xa[i].z - ca[j].z);
                    acc[i][j] += fabsf(xa[i].w - ca[j].w);
                }
        }
    }

    // ===== epilogue: d_pos (unique owner) + per-chunk exp-sum partials =====
    int lbls[2];
    #pragma unroll
    for (int i = 0; i < 2; i++) lbls[i] = lbl_sm[ty * 2 + i];

    #pragma unroll
    for (int i = 0; i < 2; i++) {
        float ps = 0.f;
        #pragma unroll
        for (int j = 0; j < 4; j++) {
            int cg = c0 + tx * 4 + j;
            float dist = acc[i][j];
            if (cg == lbls[i]) {
                d_pos[m0 + ty * 2 + i] = dist;        // unique writer per m
            } else {
                ps += __expf(-dist);
            }
        }
        #pragma unroll
        for (int off = 8; off > 0; off >>= 1)         // 16-lane tx group
            ps += __shfl_xor(ps, off);
        if (tx == 0)
            loss_part[(size_t)(m0 + ty * 2 + i) * 8 + cb] = ps;
    }
}

// ---- kernel 2: {gather center-update for class b} + {loss rows 8b..8b+7} ----
// grid = 512 blocks x 256 threads. Loss loads issued at entry (hide under the
// label scan + gather).
__global__ __launch_bounds__(256) void k_fin(
    const float* __restrict__ x0, const float* __restrict__ centers,
    const int* __restrict__ label,
    const float* __restrict__ d_pos, const float* __restrict__ loss_part,
    float* __restrict__ out_nc, float* __restrict__ loss_out)
{
    __shared__ int   list[1024];
    __shared__ float tmp[128];
    __shared__ int   lcount;

    int b   = blockIdx.x;
    int tid = threadIdx.x;

    // issue loss loads early (consumed at the end)
    int   m  = b * 8 + (tid >> 3);           // 8 rows per block, 8 lanes each
    float lp = 0.f, dp = 0.f;
    if (tid < 64) {
        lp = loss_part[(size_t)m * 8 + (tid & 7)];
        dp = d_pos[m];
    }

    // ----- center update for class b (LDS member list + gather) -----
    if (tid == 0) lcount = 0;
    __syncthreads();
    {
        const int4* lab4 = reinterpret_cast<const int4*>(label);
        #pragma unroll
        for (int t = 0; t < 4; ++t) {
            int4 v   = lab4[tid + 256 * t];
            int base = (tid + 256 * t) * 4;
            if (v.x == b) { int k = atomicAdd(&lcount, 1); if (k < 1024) list[k] = base + 0; }
            if (v.y == b) { int k = atomicAdd(&lcount, 1); if (k < 1024) list[k] = base + 1; }
            if (v.z == b) { int k = atomicAdd(&lcount, 1); if (k < 1024) list[k] = base + 2; }
            if (v.w == b) { int k = atomicAdd(&lcount, 1); if (k < 1024) list[k] = base + 3; }
        }
    }
    __syncthreads();
    {
        int n = min(lcount, 1024);
        int d = tid & 127;
        int p = tid >> 7;                  // 0/1: even/odd member indices
        float s = 0.f;
        int i = p;
        for (; i + 6 < n; i += 8) {        // 4 loads in flight per wait
            float a0 = x0[(size_t)list[i + 0] * D + d];
            float a1 = x0[(size_t)list[i + 2] * D + d];
            float a2 = x0[(size_t)list[i + 4] * D + d];
            float a3 = x0[(size_t)list[i + 6] * D + d];
            s += (a0 + a1) + (a2 + a3);
        }
        for (; i < n; i += 2) s += x0[(size_t)list[i] * D + d];
        if (p == 1) tmp[d] = s;
        __syncthreads();
        if (p == 0) {
            s += tmp[d];
            float ctr = centers[b * D + d];
            out_nc[b * D + d] = ctr - ALPHA * ((float)n * ctr - s) / ((float)n + 1.0f);
        }
    }

    // ----- finalize 8 losses (8-lane groups within wave 0) -----
    if (tid < 64) {
        float s = lp;
        #pragma unroll
        for (int off = 4; off > 0; off >>= 1)
            s += __shfl_xor(s, off);
        if ((tid & 7) == 0)
            loss_out[m] = dp + log1pf(s);
    }
}

extern "C" void kernel_launch(void* const* d_in, const int* in_sizes, int n_in,
                              void* d_out, int out_size, void* d_ws, size_t ws_size,
                              hipStream_t stream)
{
    const float* x0      = (const float*)d_in[0];   // (M, D)
    const float* onehot  = (const float*)d_in[1];   // (M, C)
    const float* centers = (const float*)d_in[2];   // (C, D)
    float* out = (float*)d_out;                     // [0..M) loss, [M..) new_centers

    char* ws = (char*)d_ws;
    int*   label     = (int*)  (ws + WS_LABEL);
    float* d_pos     = (float*)(ws + WS_DPOS);
    float* loss_part = (float*)(ws + WS_LPART);

    k_dist<<<1024, 256, 0, stream>>>(x0, centers, onehot, label, d_pos, loss_part);
    k_fin <<<C,    256, 0, stream>>>(x0, centers, label, d_pos, loss_part,
                                     out + M, out);
}

// Round 14
// 85.194 us; speedup vs baseline: 1.1319x; 1.0994x over previous
//
#include <hip/hip_runtime.h>
#include <hip/hip_fp16.h>
#include <math.h>

static constexpr int M = 4096;   // batch rows
static constexpr int C = 512;    // classes
static constexpr int D = 128;    // feature dim
static constexpr float ALPHA = 0.5f;

// ---------------- workspace layout (bytes) ----------------
// label     : int[M]      @ 0       fully written by k_label
// d_pos     : float[M]    @ 16384   plain-stored by unique owner thread
// loss_part : float[M*8]  @ 32768   plain-stored, one slot per (m, c-chunk)
// no zero-init, no global atomics, no fences.
static constexpr size_t WS_LABEL = 0;
static constexpr size_t WS_DPOS  = 16384;
static constexpr size_t WS_LPART = 32768;

// ---- kernel 1: per-row argmax of onehot -> label[M] ----
__global__ __launch_bounds__(256) void k_label(
    const float* __restrict__ onehot, int* __restrict__ label)
{
    int gtid = blockIdx.x * 256 + threadIdx.x;
    int row  = gtid >> 6;            // grid = M/4 -> row < M always
    int lane = threadIdx.x & 63;

    const float4* oh = reinterpret_cast<const float4*>(onehot + (size_t)row * C);
    float4 a = oh[lane * 2 + 0];
    float4 b = oh[lane * 2 + 1];
    int lbl = -1;
    if (a.x > 0.5f) lbl = lane * 8 + 0;
    if (a.y > 0.5f) lbl = lane * 8 + 1;
    if (a.z > 0.5f) lbl = lane * 8 + 2;
    if (a.w > 0.5f) lbl = lane * 8 + 3;
    if (b.x > 0.5f) lbl = lane * 8 + 4;
    if (b.y > 0.5f) lbl = lane * 8 + 5;
    if (b.z > 0.5f) lbl = lane * 8 + 6;
    if (b.w > 0.5f) lbl = lane * 8 + 7;
    #pragma unroll
    for (int off = 32; off > 0; off >>= 1)
        lbl = max(lbl, __shfl_xor(lbl, off));
    if (lane == 0) label[row] = lbl;
}

// ---- kernel 2: 32x64 L1-distance tile in FP16, single-stage full-D ----
// grid = 128 m-tiles x 8 c-chunks = 1024 blocks x 256 threads (4 blocks/CU),
// 24 KB LDS: x[32][128]h + c[64][128]h. One barrier (no dc loop). 16B LDS
// slot = 8 dims; physical slot p of row r holds logical slot p ^ (r&15),
// applied at the GLOBAL source (linear conflict-free ds_write_b128; reads
// <=2-way = free). Inner: v_pk_sub_f16 + v_and(abs) + v_pk_add_f16 per 2
// elems (1.5 inst/elem vs 2 for f32) and half the LDS bytes.
// Precision: fp16 accumulate over 128 dims (d ~ 102, err ~0.1) vs thr 2.5.
__global__ __launch_bounds__(256) void k_dist(
    const float* __restrict__ x0, const float* __restrict__ centers,
    const int* __restrict__ label,
    float* __restrict__ d_pos, float* __restrict__ loss_part)
{
    __shared__ float4 xs4[32 * 16];   // 8 KB  : 32 rows x 16 slots (8 dims ea)
    __shared__ float4 cs4[64 * 16];   // 16 KB : 64 rows x 16 slots

    int tid = threadIdx.x;
    int b   = blockIdx.x;
    int mb  = b & 127;          // 128 m tiles of 32 rows
    int cb  = b >> 7;           // 8 c chunks of 64
    int m0  = mb * 32, c0 = cb * 64;
    int tx  = tid & 15;         // -> 4 c rows
    int ty  = tid >> 4;         // -> 2 m rows

    // labels for this thread's rows (k_label ran in previous dispatch)
    int lbls[2];
    #pragma unroll
    for (int i = 0; i < 2; i++) lbls[i] = label[m0 + ty * 2 + i];

    // ===== stage x tile: 512 slots, 2 per thread (load f32, cvt, write h) ====
    #pragma unroll
    for (int kk = 0; kk < 2; ++kk) {
        int S   = kk * 256 + tid;         // physical slot 0..511
        int row = S >> 4;                 // 0..31
        int l   = (S & 15) ^ (row & 15);  // logical 8-dim group (pre-swizzle)
        const float4* p = reinterpret_cast<const float4*>(
            x0 + (size_t)(m0 + row) * D + l * 8);
        float4 v0 = p[0], v1 = p[1];
        union { __half2 h[4]; float4 f; } u;
        u.h[0] = __floats2half2_rn(v0.x, v0.y);
        u.h[1] = __floats2half2_rn(v0.z, v0.w);
        u.h[2] = __floats2half2_rn(v1.x, v1.y);
        u.h[3] = __floats2half2_rn(v1.z, v1.w);
        xs4[S] = u.f;                     // linear: conflict-free
    }
    // ===== stage c tile: 1024 slots, 4 per thread =====
    #pragma unroll
    for (int kk = 0; kk < 4; ++kk) {
        int S   = kk * 256 + tid;         // physical slot 0..1023
        int row = S >> 4;                 // 0..63
        int l   = (S & 15) ^ (row & 15);
        const float4* p = reinterpret_cast<const float4*>(
            centers + (size_t)(c0 + row) * D + l * 8);
        float4 v0 = p[0], v1 = p[1];
        union { __half2 h[4]; float4 f; } u;
        u.h[0] = __floats2half2_rn(v0.x, v0.y);
        u.h[1] = __floats2half2_rn(v0.z, v0.w);
        u.h[2] = __floats2half2_rn(v1.x, v1.y);
        u.h[3] = __floats2half2_rn(v1.z, v1.w);
        cs4[S] = u.f;
    }
    __syncthreads();

    // ===== compute: 2m x 4c per thread, 16 q-iters x 8 dims =====
    __half2 acc2[2][4];
    #pragma unroll
    for (int i = 0; i < 2; i++)
        #pragma unroll
        for (int j = 0; j < 4; j++) acc2[i][j] = __float2half2_rn(0.f);

    #pragma unroll 4
    for (int q = 0; q < 16; ++q) {
        float4 xf[2], cf[4];
        #pragma unroll
        for (int i = 0; i < 2; ++i) {
            int r = ty * 2 + i;
            xf[i] = xs4[r * 16 + (q ^ (r & 15))];
        }
        #pragma unroll
        for (int j = 0; j < 4; ++j) {
            int r = tx * 4 + j;
            cf[j] = cs4[r * 16 + (q ^ (r & 15))];
        }
        #pragma unroll
        for (int i = 0; i < 2; ++i) {
            const __half2* xh = reinterpret_cast<const __half2*>(&xf[i]);
            #pragma unroll
            for (int j = 0; j < 4; ++j) {
                const __half2* ch = reinterpret_cast<const __half2*>(&cf[j]);
                #pragma unroll
                for (int k = 0; k < 4; ++k)
                    acc2[i][j] = __hadd2(acc2[i][j],
                                         __habs2(__hsub2(xh[k], ch[k])));
            }
        }
    }

    // ===== epilogue: d_pos (unique owner) + per-chunk exp-sum partials =====
    #pragma unroll
    for (int i = 0; i < 2; i++) {
        float ps = 0.f;
        #pragma unroll
        for (int j = 0; j < 4; j++) {
            float dist = __low2float(acc2[i][j]) + __high2float(acc2[i][j]);
            int cg = c0 + tx * 4 + j;
            if (cg == lbls[i]) {
                d_pos[m0 + ty * 2 + i] = dist;        // unique writer per m
            } else {
                ps += __expf(-dist);
            }
        }
        #pragma unroll
        for (int off = 8; off > 0; off >>= 1)         // 16-lane tx group
            ps += __shfl_xor(ps, off);
        if (tx == 0)
            loss_part[(size_t)(m0 + ty * 2 + i) * 8 + cb] = ps;
    }
}

// ---- kernel 3: {gather center-update for class b} + {loss rows 8b..8b+7} ----
// grid = 512 blocks x 256 threads. Loss loads issued at entry.
__global__ __launch_bounds__(256) void k_fin(
    const float* __restrict__ x0, const float* __restrict__ centers,
    const int* __restrict__ label,
    const float* __restrict__ d_pos, const float* __restrict__ loss_part,
    float* __restrict__ out_nc, float* __restrict__ loss_out)
{
    __shared__ int   list[1024];
    __shared__ float tmp[128];
    __shared__ int   lcount;

    int b   = blockIdx.x;
    int tid = threadIdx.x;

    // issue loss loads early (consumed at the end)
    int   m  = b * 8 + (tid >> 3);           // 8 rows per block, 8 lanes each
    float lp = 0.f, dp = 0.f;
    if (tid < 64) {
        lp = loss_part[(size_t)m * 8 + (tid & 7)];
        dp = d_pos[m];
    }

    // ----- center update for class b (LDS member list + gather) -----
    if (tid == 0) lcount = 0;
    __syncthreads();
    {
        const int4* lab4 = reinterpret_cast<const int4*>(label);
        #pragma unroll
        for (int t = 0; t < 4; ++t) {
            int4 v   = lab4[tid + 256 * t];
            int base = (tid + 256 * t) * 4;
            if (v.x == b) { int k = atomicAdd(&lcount, 1); if (k < 1024) list[k] = base + 0; }
            if (v.y == b) { int k = atomicAdd(&lcount, 1); if (k < 1024) list[k] = base + 1; }
            if (v.z == b) { int k = atomicAdd(&lcount, 1); if (k < 1024) list[k] = base + 2; }
            if (v.w == b) { int k = atomicAdd(&lcount, 1); if (k < 1024) list[k] = base + 3; }
        }
    }
    __syncthreads();
    {
        int n = min(lcount, 1024);
        int d = tid & 127;
        int p = tid >> 7;                  // 0/1: even/odd member indices
        float s = 0.f;
        int i = p;
        for (; i + 6 < n; i += 8) {        // 4 loads in flight per wait
            float a0 = x0[(size_t)list[i + 0] * D + d];
            float a1 = x0[(size_t)list[i + 2] * D + d];
            float a2 = x0[(size_t)list[i + 4] * D + d];
            float a3 = x0[(size_t)list[i + 6] * D + d];
            s += (a0 + a1) + (a2 + a3);
        }
        for (; i < n; i += 2) s += x0[(size_t)list[i] * D + d];
        if (p == 1) tmp[d] = s;
        __syncthreads();
        if (p == 0) {
            s += tmp[d];
            float ctr = centers[b * D + d];
            out_nc[b * D + d] = ctr - ALPHA * ((float)n * ctr - s) / ((float)n + 1.0f);
        }
    }

    // ----- finalize 8 losses (8-lane groups within wave 0) -----
    if (tid < 64) {
        float s = lp;
        #pragma unroll
        for (int off = 4; off > 0; off >>= 1)
            s += __shfl_xor(s, off);
        if ((tid & 7) == 0)
            loss_out[m] = dp + log1pf(s);
    }
}

extern "C" void kernel_launch(void* const* d_in, const int* in_sizes, int n_in,
                              void* d_out, int out_size, void* d_ws, size_t ws_size,
                              hipStream_t stream)
{
    const float* x0      = (const float*)d_in[0];   // (M, D)
    const float* onehot  = (const float*)d_in[1];   // (M, C)
    const float* centers = (const float*)d_in[2];   // (C, D)
    float* out = (float*)d_out;                     // [0..M) loss, [M..) new_centers

    char* ws = (char*)d_ws;
    int*   label     = (int*)  (ws + WS_LABEL);
    float* d_pos     = (float*)(ws + WS_DPOS);
    float* loss_part = (float*)(ws + WS_LPART);

    k_label<<<M / 4, 256, 0, stream>>>(onehot, label);
    k_dist <<<1024,  256, 0, stream>>>(x0, centers, label, d_pos, loss_part);
    k_fin  <<<C,     256, 0, stream>>>(x0, centers, label, d_pos, loss_part,
                                       out + M, out);
}

// Round 15
// 83.068 us; speedup vs baseline: 1.1609x; 1.0256x over previous
//
#include <hip/hip_runtime.h>
#include <hip/hip_fp16.h>
#include <math.h>

static constexpr int M = 4096;   // batch rows
static constexpr int C = 512;    // classes
static constexpr int D = 128;    // feature dim
static constexpr float ALPHA = 0.5f;

// ---------------- workspace layout (bytes) ----------------
// label     : int[M]      @ 0       fully written by k_label
// d_pos     : float[M]    @ 16384   plain-stored by unique owner thread
// loss_part : float[M*8]  @ 32768   plain-stored, one slot per (m, c-chunk)
// no zero-init, no global atomics, no fences.
static constexpr size_t WS_LABEL = 0;
static constexpr size_t WS_DPOS  = 16384;
static constexpr size_t WS_LPART = 32768;

// ---- kernel 1: per-row argmax of onehot -> label[M] ----
__global__ __launch_bounds__(256) void k_label(
    const float* __restrict__ onehot, int* __restrict__ label)
{
    int gtid = blockIdx.x * 256 + threadIdx.x;
    int row  = gtid >> 6;            // grid = M/4 -> row < M always
    int lane = threadIdx.x & 63;

    const float4* oh = reinterpret_cast<const float4*>(onehot + (size_t)row * C);
    float4 a = oh[lane * 2 + 0];
    float4 b = oh[lane * 2 + 1];
    int lbl = -1;
    if (a.x > 0.5f) lbl = lane * 8 + 0;
    if (a.y > 0.5f) lbl = lane * 8 + 1;
    if (a.z > 0.5f) lbl = lane * 8 + 2;
    if (a.w > 0.5f) lbl = lane * 8 + 3;
    if (b.x > 0.5f) lbl = lane * 8 + 4;
    if (b.y > 0.5f) lbl = lane * 8 + 5;
    if (b.z > 0.5f) lbl = lane * 8 + 6;
    if (b.w > 0.5f) lbl = lane * 8 + 7;
    #pragma unroll
    for (int off = 32; off > 0; off >>= 1)
        lbl = max(lbl, __shfl_xor(lbl, off));
    if (lane == 0) label[row] = lbl;
}

// ---- kernel 2: 64x64 L1-distance tile in FP16, 4m x 4c per thread ----
// grid = 64 m-tiles x 8 c-chunks = 512 blocks x 256 threads, 32 KB LDS
// (4-5 blocks/CU by LDS). Single stage full-D, one barrier. 16B LDS slot =
// 8 dims; physical slot S of row r holds logical slot (S&15)^(r&15), swizzle
// applied at the GLOBAL source (linear conflict-free ds_write_b128; read
// pattern identical to R14's proven c-side). 0.5 LDS-reads/output (vs R14's
// 0.75) -> LDS floor ~5.1 us, balanced with the ~5.1 us fp16 VALU floor.
__global__ __launch_bounds__(256) void k_dist(
    const float* __restrict__ x0, const float* __restrict__ centers,
    const int* __restrict__ label,
    float* __restrict__ d_pos, float* __restrict__ loss_part)
{
    __shared__ float4 xs4[64 * 16];   // 16 KB : 64 rows x 16 slots (8 dims ea)
    __shared__ float4 cs4[64 * 16];   // 16 KB

    int tid = threadIdx.x;
    int b   = blockIdx.x;
    int mb  = b & 63;           // 64 m tiles of 64 rows
    int cb  = b >> 6;           // 8 c chunks of 64
    int m0  = mb * 64, c0 = cb * 64;
    int tx  = tid & 15;         // -> 4 c rows
    int ty  = tid >> 4;         // -> 4 m rows

    // labels for this thread's 4 m-rows (k_label ran in previous dispatch)
    int lbls[4];
    #pragma unroll
    for (int i = 0; i < 4; i++) lbls[i] = label[m0 + ty * 4 + i];

    // ===== stage x tile: 1024 slots, 4 per thread (load f32, cvt, write h) ===
    #pragma unroll
    for (int kk = 0; kk < 4; ++kk) {
        int S   = kk * 256 + tid;         // physical slot 0..1023
        int row = S >> 4;                 // 0..63
        int l   = (S & 15) ^ (row & 15);  // logical 8-dim group (pre-swizzle)
        const float4* p = reinterpret_cast<const float4*>(
            x0 + (size_t)(m0 + row) * D + l * 8);
        float4 v0 = p[0], v1 = p[1];
        union { __half2 h[4]; float4 f; } u;
        u.h[0] = __floats2half2_rn(v0.x, v0.y);
        u.h[1] = __floats2half2_rn(v0.z, v0.w);
        u.h[2] = __floats2half2_rn(v1.x, v1.y);
        u.h[3] = __floats2half2_rn(v1.z, v1.w);
        xs4[S] = u.f;                     // linear: conflict-free
    }
    // ===== stage c tile: 1024 slots, 4 per thread =====
    #pragma unroll
    for (int kk = 0; kk < 4; ++kk) {
        int S   = kk * 256 + tid;
        int row = S >> 4;
        int l   = (S & 15) ^ (row & 15);
        const float4* p = reinterpret_cast<const float4*>(
            centers + (size_t)(c0 + row) * D + l * 8);
        float4 v0 = p[0], v1 = p[1];
        union { __half2 h[4]; float4 f; } u;
        u.h[0] = __floats2half2_rn(v0.x, v0.y);
        u.h[1] = __floats2half2_rn(v0.z, v0.w);
        u.h[2] = __floats2half2_rn(v1.x, v1.y);
        u.h[3] = __floats2half2_rn(v1.z, v1.w);
        cs4[S] = u.f;
    }
    __syncthreads();

    // ===== compute: 4m x 4c per thread, 16 q-iters x 8 dims =====
    __half2 acc2[4][4];
    #pragma unroll
    for (int i = 0; i < 4; i++)
        #pragma unroll
        for (int j = 0; j < 4; j++) acc2[i][j] = __float2half2_rn(0.f);

    #pragma unroll 4
    for (int q = 0; q < 16; ++q) {
        float4 xf[4], cf[4];
        #pragma unroll
        for (int i = 0; i < 4; ++i) {
            int r = ty * 4 + i;
            xf[i] = xs4[r * 16 + (q ^ (r & 15))];
        }
        #pragma unroll
        for (int j = 0; j < 4; ++j) {
            int r = tx * 4 + j;
            cf[j] = cs4[r * 16 + (q ^ (r & 15))];
        }
        #pragma unroll
        for (int i = 0; i < 4; ++i) {
            const __half2* xh = reinterpret_cast<const __half2*>(&xf[i]);
            #pragma unroll
            for (int j = 0; j < 4; ++j) {
                const __half2* ch = reinterpret_cast<const __half2*>(&cf[j]);
                #pragma unroll
                for (int k = 0; k < 4; ++k)
                    acc2[i][j] = __hadd2(acc2[i][j],
                                         __habs2(__hsub2(xh[k], ch[k])));
            }
        }
    }

    // ===== epilogue: d_pos (unique owner) + per-chunk exp-sum partials =====
    #pragma unroll
    for (int i = 0; i < 4; i++) {
        float ps = 0.f;
        #pragma unroll
        for (int j = 0; j < 4; j++) {
            float dist = __low2float(acc2[i][j]) + __high2float(acc2[i][j]);
            int cg = c0 + tx * 4 + j;
            if (cg == lbls[i]) {
                d_pos[m0 + ty * 4 + i] = dist;        // unique writer per m
            } else {
                ps += __expf(-dist);
            }
        }
        #pragma unroll
        for (int off = 8; off > 0; off >>= 1)         // 16-lane tx group
            ps += __shfl_xor(ps, off);
        if (tx == 0)
            loss_part[(size_t)(m0 + ty * 4 + i) * 8 + cb] = ps;
    }
}

// ---- kernel 3: {gather center-update for class b} + {loss rows 8b..8b+7} ----
// grid = 512 blocks x 256 threads. Loss loads issued at entry.
__global__ __launch_bounds__(256) void k_fin(
    const float* __restrict__ x0, const float* __restrict__ centers,
    const int* __restrict__ label,
    const float* __restrict__ d_pos, const float* __restrict__ loss_part,
    float* __restrict__ out_nc, float* __restrict__ loss_out)
{
    __shared__ int   list[1024];
    __shared__ float tmp[128];
    __shared__ int   lcount;

    int b   = blockIdx.x;
    int tid = threadIdx.x;

    // issue loss loads early (consumed at the end)
    int   m  = b * 8 + (tid >> 3);           // 8 rows per block, 8 lanes each
    float lp = 0.f, dp = 0.f;
    if (tid < 64) {
        lp = loss_part[(size_t)m * 8 + (tid & 7)];
        dp = d_pos[m];
    }

    // ----- center update for class b (LDS member list + gather) -----
    if (tid == 0) lcount = 0;
    __syncthreads();
    {
        const int4* lab4 = reinterpret_cast<const int4*>(label);
        #pragma unroll
        for (int t = 0; t < 4; ++t) {
            int4 v   = lab4[tid + 256 * t];
            int base = (tid + 256 * t) * 4;
            if (v.x == b) { int k = atomicAdd(&lcount, 1); if (k < 1024) list[k] = base + 0; }
            if (v.y == b) { int k = atomicAdd(&lcount, 1); if (k < 1024) list[k] = base + 1; }
            if (v.z == b) { int k = atomicAdd(&lcount, 1); if (k < 1024) list[k] = base + 2; }
            if (v.w == b) { int k = atomicAdd(&lcount, 1); if (k < 1024) list[k] = base + 3; }
        }
    }
    __syncthreads();
    {
        int n = min(lcount, 1024);
        int d = tid & 127;
        int p = tid >> 7;                  // 0/1: even/odd member indices
        float s = 0.f;
        int i = p;
        for (; i + 6 < n; i += 8) {        // 4 loads in flight per wait
            float a0 = x0[(size_t)list[i + 0] * D + d];
            float a1 = x0[(size_t)list[i + 2] * D + d];
            float a2 = x0[(size_t)list[i + 4] * D + d];
            float a3 = x0[(size_t)list[i + 6] * D + d];
            s += (a0 + a1) + (a2 + a3);
        }
        for (; i < n; i += 2) s += x0[(size_t)list[i] * D + d];
        if (p == 1) tmp[d] = s;
        __syncthreads();
        if (p == 0) {
            s += tmp[d];
            float ctr = centers[b * D + d];
            out_nc[b * D + d] = ctr - ALPHA * ((float)n * ctr - s) / ((float)n + 1.0f);
        }
    }

    // ----- finalize 8 losses (8-lane groups within wave 0) -----
    if (tid < 64) {
        float s = lp;
        #pragma unroll
        for (int off = 4; off > 0; off >>= 1)
            s += __shfl_xor(s, off);
        if ((tid & 7) == 0)
            loss_out[m] = dp + log1pf(s);
    }
}

extern "C" void kernel_launch(void* const* d_in, const int* in_sizes, int n_in,
                              void* d_out, int out_size, void* d_ws, size_t ws_size,
                              hipStream_t stream)
{
    const float* x0      = (const float*)d_in[0];   // (M, D)
    const float* onehot  = (const float*)d_in[1];   // (M, C)
    const float* centers = (const float*)d_in[2];   // (C, D)
    float* out = (float*)d_out;                     // [0..M) loss, [M..) new_centers

    char* ws = (char*)d_ws;
    int*   label     = (int*)  (ws + WS_LABEL);
    float* d_pos     = (float*)(ws + WS_DPOS);
    float* loss_part = (float*)(ws + WS_LPART);

    k_label<<<M / 4, 256, 0, stream>>>(onehot, label);
    k_dist <<<512,   256, 0, stream>>>(x0, centers, label, d_pos, loss_part);
    k_fin  <<<C,     256, 0, stream>>>(x0, centers, label, d_pos, loss_part,
                                       out + M, out);
}